// Round 1
// baseline (587.907 us; speedup 1.0000x reference)
//
#include <hip/hip_runtime.h>
#include <math.h>

#define HW 409600
#define BB 16
#define CPRED 6
#define NKER 5
#define NBINS 2048
#define CHUNKS 64
#define EPSF 1e-6f

__device__ __forceinline__ float sigmoidf_(float x) {
    return 1.0f / (1.0f + __expf(-x));
}

__global__ __launch_bounds__(256) void pass1_kernel(
    const float* __restrict__ pred, const float* __restrict__ gt_text,
    const float* __restrict__ gt_k, const float* __restrict__ tmask,
    float* __restrict__ hist_cnt, float* __restrict__ hist_p2,
    float* __restrict__ bstats, float* __restrict__ kstats)
{
    __shared__ float s_cnt[NBINS];
    __shared__ float s_p2[NBINS];
    const int b = blockIdx.y;
    const int chunk = blockIdx.x;
    const int tid = threadIdx.x;

    for (int i = tid; i < NBINS; i += 256) { s_cnt[i] = 0.f; s_p2[i] = 0.f; }
    __syncthreads();

    const float* pt = pred + (size_t)b * CPRED * HW;
    const float* gt = gt_text + (size_t)b * HW;
    const float* tm = tmask + (size_t)b * HW;
    const float* gk = gt_k + (size_t)b * NKER * HW;

    const int start = chunk * (HW / CHUNKS);
    const int end = start + (HW / CHUNKS);

    float n_pos = 0.f, n_neg = 0.f, sp = 0.f, sp2 = 0.f;
    float kin[NKER], kui[NKER], kut[NKER];
    #pragma unroll
    for (int c = 0; c < NKER; ++c) { kin[c] = 0.f; kui[c] = 0.f; kut[c] = 0.f; }

    for (int i = start + tid; i < end; i += 256) {
        float m = tm[i];
        bool mv = m > 0.5f;
        float x = pt[i];
        float p = sigmoidf_(x);
        float g = gt[i];
        if (mv) {
            if (g > 0.5f) {
                n_pos += 1.f; sp += p; sp2 += p * p;
            } else {
                n_neg += 1.f;
                int bin = (int)(p * (float)NBINS);
                bin = bin < 0 ? 0 : (bin > NBINS - 1 ? NBINS - 1 : bin);
                atomicAdd(&s_cnt[bin], 1.f);
                atomicAdd(&s_p2[bin], p * p);
            }
        }
        #pragma unroll
        for (int c = 0; c < NKER; ++c) {
            float xk = pt[(size_t)(c + 1) * HW + i];
            float pk = sigmoidf_(xk);
            float gg = gk[(size_t)c * HW + i];
            if (mv) {
                kin[c] += pk * gg;
                kui[c] += pk * pk;
                kut[c] += gg * gg;
            }
        }
    }

    // wave-level reductions, one atomic per wave per quantity
    const int lane = tid & 63;
    #define WRED(v) { for (int o_ = 32; o_ > 0; o_ >>= 1) v += __shfl_down(v, o_, 64); }
    WRED(n_pos) WRED(n_neg) WRED(sp) WRED(sp2)
    if (lane == 0) {
        atomicAdd(&bstats[b * 4 + 0], n_pos);
        atomicAdd(&bstats[b * 4 + 1], n_neg);
        atomicAdd(&bstats[b * 4 + 2], sp);
        atomicAdd(&bstats[b * 4 + 3], sp2);
    }
    #pragma unroll
    for (int c = 0; c < NKER; ++c) {
        float a = kin[c], u = kui[c], t = kut[c];
        WRED(a) WRED(u) WRED(t)
        if (lane == 0) {
            atomicAdd(&kstats[(b * NKER + c) * 3 + 0], a);
            atomicAdd(&kstats[(b * NKER + c) * 3 + 1], u);
            atomicAdd(&kstats[(b * NKER + c) * 3 + 2], t);
        }
    }
    #undef WRED

    __syncthreads();
    for (int i = tid; i < NBINS; i += 256) {
        float c = s_cnt[i];
        if (c != 0.f) {
            atomicAdd(&hist_cnt[b * NBINS + i], c);
            atomicAdd(&hist_p2[b * NBINS + i], s_p2[i]);
        }
    }
}

__global__ __launch_bounds__(1024) void finalize_kernel(
    const float* __restrict__ hist_cnt, const float* __restrict__ hist_p2,
    const float* __restrict__ bstats, const float* __restrict__ kstats,
    float* __restrict__ out)
{
    __shared__ float s_cg[BB][64];
    __shared__ float s_pg[BB][64];
    __shared__ float s_text[BB];
    __shared__ float s_kterm[BB * NKER];

    const int tid = threadIdx.x;
    const int w = tid >> 6;      // batch index, 16 waves
    const int lane = tid & 63;
    const int GB = NBINS / 64;   // 32 bins per lane-group

    float cg = 0.f, pg = 0.f;
    for (int k = 0; k < GB; ++k) {
        int idx = w * NBINS + lane * GB + k;
        cg += hist_cnt[idx];
        pg += hist_p2[idx];
    }
    s_cg[w][lane] = cg;
    s_pg[w][lane] = pg;
    __syncthreads();

    if (lane == 0) {
        const int b = w;
        float n_pos = bstats[b * 4 + 0];
        float n_negt = bstats[b * 4 + 1];
        float sp = bstats[b * 4 + 2];
        float sp2 = bstats[b * 4 + 3];
        float n_sel = fminf(3.0f * n_pos, n_negt);

        // suffix scan from highest scores down: find group containing crossing
        float run = 0.f, runp2 = 0.f;
        int gsel = -1;
        for (int g = 63; g >= 0; --g) {
            float c = s_cg[b][g];
            if (run + c >= n_sel) { gsel = g; break; }
            run += c; runp2 += s_pg[b][g];
        }
        float hard_p2 = runp2;
        if (gsel >= 0) {
            bool done = false;
            for (int k = GB - 1; k >= 0 && !done; --k) {
                int idx = b * NBINS + gsel * GB + k;
                float c = hist_cnt[idx];
                float pp = hist_p2[idx];
                if (run + c >= n_sel) {
                    float need = n_sel - run;
                    hard_p2 = runp2 + (c > 0.f ? pp * (need / c) : 0.f);
                    done = true;
                } else {
                    run += c; runp2 += pp; hard_p2 = runp2;
                }
            }
        }
        float inter = sp;
        float uni = sp2 + n_pos + hard_p2 + EPSF;
        s_text[b] = 1.0f - 2.0f * inter / uni;
    }
    __syncthreads();

    if (tid < BB * NKER) {
        float a = kstats[tid * 3 + 0];
        float u = kstats[tid * 3 + 1];
        float t = kstats[tid * 3 + 2];
        s_kterm[tid] = 1.0f - 2.0f * a / (u + t + EPSF);
    }
    __syncthreads();

    if (tid == 0) {
        float lt = 0.f;
        for (int b2 = 0; b2 < BB; ++b2) lt += s_text[b2];
        lt /= (float)BB;
        float lk = 0.f;
        for (int j = 0; j < BB * NKER; ++j) lk += s_kterm[j];
        lk /= (float)(BB * NKER);
        out[0] = lk + 0.5f * lt;
        out[1] = lt;
        out[2] = lk;
    }
}

extern "C" void kernel_launch(void* const* d_in, const int* in_sizes, int n_in,
                              void* d_out, int out_size, void* d_ws, size_t ws_size,
                              hipStream_t stream)
{
    const float* pred    = (const float*)d_in[0];
    const float* gt_text = (const float*)d_in[1];
    const float* gt_k    = (const float*)d_in[2];
    const float* tmask   = (const float*)d_in[3];

    float* ws = (float*)d_ws;
    float* hist_cnt = ws;
    float* hist_p2  = ws + (size_t)BB * NBINS;
    float* bstats   = ws + (size_t)2 * BB * NBINS;
    float* kstats   = bstats + BB * 4;

    size_t zero_bytes = ((size_t)2 * BB * NBINS + BB * 4 + BB * NKER * 3) * sizeof(float);
    hipMemsetAsync(d_ws, 0, zero_bytes, stream);

    dim3 grid(CHUNKS, BB), block(256);
    hipLaunchKernelGGL(pass1_kernel, grid, block, 0, stream,
                       pred, gt_text, gt_k, tmask, hist_cnt, hist_p2, bstats, kstats);
    hipLaunchKernelGGL(finalize_kernel, dim3(1), dim3(1024), 0, stream,
                       hist_cnt, hist_p2, bstats, kstats, (float*)d_out);
}

// Round 2
// 375.477 us; speedup vs baseline: 1.5658x; 1.5658x over previous
//
#include <hip/hip_runtime.h>
#include <math.h>

#define HW 409600
#define BB 16
#define CPRED 6
#define NKER 5
#define NBINS 2048
#define CHUNKS 128
#define EPSF 1e-6f

__device__ __forceinline__ float sigmoidf_(float x) {
    return 1.0f / (1.0f + __expf(-x));
}

__device__ __forceinline__ void proc_text(float m, float x, float g,
    float& n_pos, float& n_neg, float& sp, float& sp2,
    float* s_cnt, float* s_p2)
{
    if (m > 0.5f) {
        float p = sigmoidf_(x);
        if (g > 0.5f) {
            n_pos += 1.f; sp += p; sp2 += p * p;
        } else {
            n_neg += 1.f;
            int bin = (int)(p * (float)NBINS);
            bin = bin < 0 ? 0 : (bin > NBINS - 1 ? NBINS - 1 : bin);
            atomicAdd(&s_cnt[bin], 1.f);
            atomicAdd(&s_p2[bin], p * p);
        }
    }
}

__global__ __launch_bounds__(256) void pass1_kernel(
    const float* __restrict__ pred, const float* __restrict__ gt_text,
    const float* __restrict__ gt_k, const float* __restrict__ tmask,
    float* __restrict__ hist_cnt, float* __restrict__ hist_p2,
    float* __restrict__ bstats, float* __restrict__ kstats)
{
    __shared__ float s_cnt[NBINS];
    __shared__ float s_p2[NBINS];
    __shared__ float s_red[19][4];

    const int b = blockIdx.y;
    const int chunk = blockIdx.x;
    const int tid = threadIdx.x;

    for (int i = tid; i < NBINS; i += 256) { s_cnt[i] = 0.f; s_p2[i] = 0.f; }
    __syncthreads();

    const int NV4 = HW / 4;               // 102400 float4 per (b, channel)
    const float4* tm4 = reinterpret_cast<const float4*>(tmask + (size_t)b * HW);
    const float4* gt4 = reinterpret_cast<const float4*>(gt_text + (size_t)b * HW);
    const float4* pt4 = reinterpret_cast<const float4*>(pred + (size_t)b * CPRED * HW);
    const float4* gk4 = reinterpret_cast<const float4*>(gt_k + (size_t)b * NKER * HW);

    const int per = NV4 / CHUNKS;         // 800
    const int i0 = chunk * per;
    const int i1 = i0 + per;

    float n_pos = 0.f, n_neg = 0.f, sp = 0.f, sp2 = 0.f;
    float kin[NKER], kui[NKER], kut[NKER];
    #pragma unroll
    for (int c = 0; c < NKER; ++c) { kin[c] = 0.f; kui[c] = 0.f; kut[c] = 0.f; }

    for (int i = i0 + tid; i < i1; i += 256) {
        float4 m4 = tm4[i];
        float4 g4 = gt4[i];
        float4 x4 = pt4[i];

        proc_text(m4.x, x4.x, g4.x, n_pos, n_neg, sp, sp2, s_cnt, s_p2);
        proc_text(m4.y, x4.y, g4.y, n_pos, n_neg, sp, sp2, s_cnt, s_p2);
        proc_text(m4.z, x4.z, g4.z, n_pos, n_neg, sp, sp2, s_cnt, s_p2);
        proc_text(m4.w, x4.w, g4.w, n_pos, n_neg, sp, sp2, s_cnt, s_p2);

        float mb0 = m4.x > 0.5f ? 1.f : 0.f;
        float mb1 = m4.y > 0.5f ? 1.f : 0.f;
        float mb2 = m4.z > 0.5f ? 1.f : 0.f;
        float mb3 = m4.w > 0.5f ? 1.f : 0.f;

        #pragma unroll
        for (int c = 0; c < NKER; ++c) {
            float4 xk = pt4[(size_t)(c + 1) * NV4 + i];
            float4 gg = gk4[(size_t)c * NV4 + i];
            float p0 = sigmoidf_(xk.x), p1 = sigmoidf_(xk.y);
            float p2 = sigmoidf_(xk.z), p3 = sigmoidf_(xk.w);
            kin[c] += mb0 * p0 * gg.x + mb1 * p1 * gg.y
                    + mb2 * p2 * gg.z + mb3 * p3 * gg.w;
            kui[c] += mb0 * p0 * p0 + mb1 * p1 * p1
                    + mb2 * p2 * p2 + mb3 * p3 * p3;
            // gg is binary: g*g == g
            kut[c] += mb0 * gg.x + mb1 * gg.y + mb2 * gg.z + mb3 * gg.w;
        }
    }

    // wave-level reduction
    const int lane = tid & 63;
    const int wv = tid >> 6;   // 0..3
    #define WRED(v) { for (int o_ = 32; o_ > 0; o_ >>= 1) v += __shfl_down(v, o_, 64); }
    WRED(n_pos) WRED(n_neg) WRED(sp) WRED(sp2)
    if (lane == 0) {
        s_red[0][wv] = n_pos; s_red[1][wv] = n_neg;
        s_red[2][wv] = sp;    s_red[3][wv] = sp2;
    }
    #pragma unroll
    for (int c = 0; c < NKER; ++c) {
        float a = kin[c], u = kui[c], t = kut[c];
        WRED(a) WRED(u) WRED(t)
        if (lane == 0) {
            s_red[4 + c * 3 + 0][wv] = a;
            s_red[4 + c * 3 + 1][wv] = u;
            s_red[4 + c * 3 + 2][wv] = t;
        }
    }
    #undef WRED
    __syncthreads();

    // one global atomic per quantity per block
    if (tid < 19) {
        float a = s_red[tid][0] + s_red[tid][1] + s_red[tid][2] + s_red[tid][3];
        float* dst;
        if (tid < 4) dst = &bstats[b * 4 + tid];
        else {
            int q = tid - 4;
            dst = &kstats[(b * NKER + q / 3) * 3 + (q % 3)];
        }
        atomicAdd(dst, a);
    }

    // flush histogram
    for (int i = tid; i < NBINS; i += 256) {
        float c = s_cnt[i];
        if (c != 0.f) {
            atomicAdd(&hist_cnt[b * NBINS + i], c);
            atomicAdd(&hist_p2[b * NBINS + i], s_p2[i]);
        }
    }
}

__global__ __launch_bounds__(1024) void finalize_kernel(
    const float* __restrict__ hist_cnt, const float* __restrict__ hist_p2,
    const float* __restrict__ bstats, const float* __restrict__ kstats,
    float* __restrict__ out)
{
    __shared__ float s_text[BB];
    __shared__ float s_kterm[BB * NKER];

    const int tid = threadIdx.x;
    const int w = tid >> 6;          // batch, 16 waves
    const int lane = tid & 63;
    const int SEG = NBINS / 64;      // 32 bins per lane

    // per-lane segment sums (lane l owns bins [l*SEG, l*SEG+SEG))
    float cg = 0.f, pg = 0.f;
    {
        int base = w * NBINS + lane * SEG;
        for (int k = 0; k < SEG; ++k) {
            cg += hist_cnt[base + k];
            pg += hist_p2[base + k];
        }
    }
    // inclusive prefix over lanes (ascending)
    float pc = cg, pp = pg;
    #pragma unroll
    for (int o = 1; o < 64; o <<= 1) {
        float tc = __shfl_up(pc, o, 64);
        float tp = __shfl_up(pp, o, 64);
        if (lane >= o) { pc += tc; pp += tp; }
    }
    float totc = __shfl(pc, 63, 64);
    float totp = __shfl(pp, 63, 64);
    float sufc = totc - pc;   // sum over lanes > lane (higher-score segments)
    float sufp = totp - pp;

    float n_pos  = bstats[w * 4 + 0];
    float n_negt = bstats[w * 4 + 1];
    float sp     = bstats[w * 4 + 2];
    float sp2    = bstats[w * 4 + 3];
    float n_sel  = fminf(3.0f * n_pos, n_negt);

    float hard_p2 = 0.f;
    bool cross = (sufc < n_sel) && (sufc + cg >= n_sel);
    unsigned long long bal = __ballot(cross);
    if (n_sel <= 0.f) {
        hard_p2 = 0.f;
    } else if (bal == 0ULL) {
        hard_p2 = totp;   // all negatives selected
    } else {
        int ls = 63 - __builtin_clzll(bal);   // uniform across wave
        float run  = __shfl(sufc, ls, 64);    // cumulative above segment
        float runp = __shfl(sufp, ls, 64);
        // per-bin detail inside segment ls, held in lanes 0..SEG-1
        float bc = 0.f, bp = 0.f;
        if (lane < SEG) {
            int idx = w * NBINS + ls * SEG + lane;
            bc = hist_cnt[idx];
            bp = hist_p2[idx];
        }
        float pc2 = bc, pp2 = bp;
        #pragma unroll
        for (int o = 1; o < 64; o <<= 1) {
            float tc = __shfl_up(pc2, o, 64);
            float tp = __shfl_up(pp2, o, 64);
            if (lane >= o) { pc2 += tc; pp2 += tp; }
        }
        float tot2c = __shfl(pc2, SEG - 1, 64);
        float tot2p = __shfl(pp2, SEG - 1, 64);
        float suf2c = tot2c - pc2;  // within-segment suffix (bins above this one)
        float suf2p = tot2p - pp2;
        bool cross2 = (lane < SEG) && (run + suf2c < n_sel) && (run + suf2c + bc >= n_sel);
        unsigned long long bal2 = __ballot(cross2);
        if (bal2 == 0ULL) {
            hard_p2 = runp + tot2p;
        } else {
            int ks = 63 - __builtin_clzll(bal2);
            float rs  = __shfl(suf2c, ks, 64);
            float rsp = __shfl(suf2p, ks, 64);
            float cc  = __shfl(bc, ks, 64);
            float cp  = __shfl(bp, ks, 64);
            float need = n_sel - (run + rs);
            hard_p2 = runp + rsp + (cc > 0.f ? cp * (need / cc) : 0.f);
        }
    }

    if (lane == 0) {
        float uni = sp2 + n_pos + hard_p2 + EPSF;
        s_text[w] = 1.0f - 2.0f * sp / uni;
    }
    __syncthreads();

    if (tid < BB * NKER) {
        float a = kstats[tid * 3 + 0];
        float u = kstats[tid * 3 + 1];
        float t = kstats[tid * 3 + 2];
        s_kterm[tid] = 1.0f - 2.0f * a / (u + t + EPSF);
    }
    __syncthreads();

    if (tid == 0) {
        float lt = 0.f;
        for (int b2 = 0; b2 < BB; ++b2) lt += s_text[b2];
        lt /= (float)BB;
        float lk = 0.f;
        for (int j = 0; j < BB * NKER; ++j) lk += s_kterm[j];
        lk /= (float)(BB * NKER);
        out[0] = lk + 0.5f * lt;
        out[1] = lt;
        out[2] = lk;
    }
}

extern "C" void kernel_launch(void* const* d_in, const int* in_sizes, int n_in,
                              void* d_out, int out_size, void* d_ws, size_t ws_size,
                              hipStream_t stream)
{
    const float* pred    = (const float*)d_in[0];
    const float* gt_text = (const float*)d_in[1];
    const float* gt_k    = (const float*)d_in[2];
    const float* tmask   = (const float*)d_in[3];

    float* ws = (float*)d_ws;
    float* hist_cnt = ws;
    float* hist_p2  = ws + (size_t)BB * NBINS;
    float* bstats   = ws + (size_t)2 * BB * NBINS;
    float* kstats   = bstats + BB * 4;

    size_t zero_bytes = ((size_t)2 * BB * NBINS + BB * 4 + BB * NKER * 3) * sizeof(float);
    hipMemsetAsync(d_ws, 0, zero_bytes, stream);

    dim3 grid(CHUNKS, BB), block(256);
    hipLaunchKernelGGL(pass1_kernel, grid, block, 0, stream,
                       pred, gt_text, gt_k, tmask, hist_cnt, hist_p2, bstats, kstats);
    hipLaunchKernelGGL(finalize_kernel, dim3(1), dim3(1024), 0, stream,
                       hist_cnt, hist_p2, bstats, kstats, (float*)d_out);
}

// Round 3
// 372.927 us; speedup vs baseline: 1.5765x; 1.0068x over previous
//
#include <hip/hip_runtime.h>
#include <math.h>

#define HW 409600
#define BB 16
#define CPRED 6
#define NKER 5
#define NBINS 1024
#define CHUNKS 128
#define EPSF 1e-6f

__device__ __forceinline__ float sigmoidf_(float x) {
    return __builtin_amdgcn_rcpf(1.0f + __expf(-x));
}

__global__ __launch_bounds__(256, 8) void pass1_kernel(
    const float* __restrict__ pred, const float* __restrict__ gt_text,
    const float* __restrict__ gt_k, const float* __restrict__ tmask,
    float* __restrict__ hist_cnt, float* __restrict__ hist_p2,
    float* __restrict__ bstats, float* __restrict__ kstats)
{
    __shared__ float s_cnt[NBINS + 1];   // last slot = trash bin
    __shared__ float s_p2[NBINS + 1];
    __shared__ float s_red[19][4];

    const int b = blockIdx.y;
    const int chunk = blockIdx.x;
    const int tid = threadIdx.x;

    for (int i = tid; i <= NBINS; i += 256) { s_cnt[i] = 0.f; s_p2[i] = 0.f; }
    __syncthreads();

    const int NV4 = HW / 4;   // 102400
    const float4* tm4 = reinterpret_cast<const float4*>(tmask + (size_t)b * HW);
    const float4* gt4 = reinterpret_cast<const float4*>(gt_text + (size_t)b * HW);
    const float4* pt4 = reinterpret_cast<const float4*>(pred + (size_t)b * CPRED * HW);
    const float4* gk4 = reinterpret_cast<const float4*>(gt_k + (size_t)b * NKER * HW);

    const int per = NV4 / CHUNKS;   // 800
    const int i0 = chunk * per;
    const int i1 = i0 + per;

    float n_pos = 0.f, n_neg = 0.f, sp = 0.f, sp2 = 0.f;
    float kin[NKER], kui[NKER], kut[NKER];
    #pragma unroll
    for (int c = 0; c < NKER; ++c) { kin[c] = 0.f; kui[c] = 0.f; kut[c] = 0.f; }

    for (int i = i0 + tid; i < i1; i += 256) {
        // ---- issue ALL 13 loads up front (independent, max MLP) ----
        float4 m4  = tm4[i];
        float4 g4  = gt4[i];
        float4 x4  = pt4[i];
        float4 xk0 = pt4[(size_t)1 * NV4 + i];
        float4 xk1 = pt4[(size_t)2 * NV4 + i];
        float4 xk2 = pt4[(size_t)3 * NV4 + i];
        float4 xk3 = pt4[(size_t)4 * NV4 + i];
        float4 xk4 = pt4[(size_t)5 * NV4 + i];
        float4 gg0 = gk4[(size_t)0 * NV4 + i];
        float4 gg1 = gk4[(size_t)1 * NV4 + i];
        float4 gg2 = gk4[(size_t)2 * NV4 + i];
        float4 gg3 = gk4[(size_t)3 * NV4 + i];
        float4 gg4 = gk4[(size_t)4 * NV4 + i];

        // ---- text channel: fully branchless (m,g are exact {0,1}) ----
        #define TEXT1(mm, xx, ggt) { \
            float p = sigmoidf_(xx); \
            float posf = (mm) * (ggt); \
            float negf = (mm) - posf; \
            float pp_ = p * p; \
            n_pos += posf; n_neg += negf; \
            sp += posf * p; sp2 += posf * pp_; \
            int bin = (int)(p * (float)NBINS); \
            bin = bin > NBINS - 1 ? NBINS - 1 : bin; \
            bin = negf > 0.f ? bin : NBINS; \
            atomicAdd(&s_cnt[bin], 1.f); \
            atomicAdd(&s_p2[bin], pp_); \
        }
        TEXT1(m4.x, x4.x, g4.x)
        TEXT1(m4.y, x4.y, g4.y)
        TEXT1(m4.z, x4.z, g4.z)
        TEXT1(m4.w, x4.w, g4.w)
        #undef TEXT1

        // ---- kernel channels: branchless FMA streams ----
        #define KCH(c, xk, gg) { \
            float p0 = sigmoidf_(xk.x), p1 = sigmoidf_(xk.y); \
            float p2_ = sigmoidf_(xk.z), p3 = sigmoidf_(xk.w); \
            kin[c] += m4.x * p0 * gg.x + m4.y * p1 * gg.y \
                    + m4.z * p2_ * gg.z + m4.w * p3 * gg.w; \
            kui[c] += m4.x * p0 * p0 + m4.y * p1 * p1 \
                    + m4.z * p2_ * p2_ + m4.w * p3 * p3; \
            kut[c] += m4.x * gg.x + m4.y * gg.y + m4.z * gg.z + m4.w * gg.w; \
        }
        KCH(0, xk0, gg0)
        KCH(1, xk1, gg1)
        KCH(2, xk2, gg2)
        KCH(3, xk3, gg3)
        KCH(4, xk4, gg4)
        #undef KCH
    }

    // wave-level reduction → LDS → one global atomic per quantity per block
    const int lane = tid & 63;
    const int wv = tid >> 6;
    #define WRED(v) { for (int o_ = 32; o_ > 0; o_ >>= 1) v += __shfl_down(v, o_, 64); }
    WRED(n_pos) WRED(n_neg) WRED(sp) WRED(sp2)
    if (lane == 0) {
        s_red[0][wv] = n_pos; s_red[1][wv] = n_neg;
        s_red[2][wv] = sp;    s_red[3][wv] = sp2;
    }
    #pragma unroll
    for (int c = 0; c < NKER; ++c) {
        float a = kin[c], u = kui[c], t = kut[c];
        WRED(a) WRED(u) WRED(t)
        if (lane == 0) {
            s_red[4 + c * 3 + 0][wv] = a;
            s_red[4 + c * 3 + 1][wv] = u;
            s_red[4 + c * 3 + 2][wv] = t;
        }
    }
    #undef WRED
    __syncthreads();

    if (tid < 19) {
        float a = s_red[tid][0] + s_red[tid][1] + s_red[tid][2] + s_red[tid][3];
        float* dst;
        if (tid < 4) dst = &bstats[b * 4 + tid];
        else {
            int q = tid - 4;
            dst = &kstats[(b * NKER + q / 3) * 3 + (q % 3)];
        }
        atomicAdd(dst, a);
    }

    // flush histogram (skip trash bin)
    for (int i = tid; i < NBINS; i += 256) {
        float c = s_cnt[i];
        if (c != 0.f) {
            atomicAdd(&hist_cnt[b * NBINS + i], c);
            atomicAdd(&hist_p2[b * NBINS + i], s_p2[i]);
        }
    }
}

// one block (1 wave) per batch
__global__ __launch_bounds__(64) void finalize_batch_kernel(
    const float* __restrict__ hist_cnt, const float* __restrict__ hist_p2,
    const float* __restrict__ bstats, const float* __restrict__ kstats,
    float* __restrict__ btext, float* __restrict__ bkterm)
{
    const int b = blockIdx.x;
    const int lane = threadIdx.x;
    const int SEG = NBINS / 64;   // 16 bins per lane

    float cg = 0.f, pg = 0.f;
    {
        int base = b * NBINS + lane * SEG;
        #pragma unroll
        for (int k = 0; k < SEG; ++k) {
            cg += hist_cnt[base + k];
            pg += hist_p2[base + k];
        }
    }
    // inclusive prefix over lanes (ascending bin order)
    float pc = cg, pp = pg;
    #pragma unroll
    for (int o = 1; o < 64; o <<= 1) {
        float tc = __shfl_up(pc, o, 64);
        float tp = __shfl_up(pp, o, 64);
        if (lane >= o) { pc += tc; pp += tp; }
    }
    float totc = __shfl(pc, 63, 64);
    float totp = __shfl(pp, 63, 64);
    float sufc = totc - pc;   // mass in higher-score segments
    float sufp = totp - pp;

    float n_pos  = bstats[b * 4 + 0];
    float n_negt = bstats[b * 4 + 1];
    float sp     = bstats[b * 4 + 2];
    float sp2    = bstats[b * 4 + 3];
    float n_sel  = fminf(3.0f * n_pos, n_negt);

    float hard_p2 = 0.f;
    bool cross = (sufc < n_sel) && (sufc + cg >= n_sel);
    unsigned long long bal = __ballot(cross);
    if (n_sel <= 0.f) {
        hard_p2 = 0.f;
    } else if (bal == 0ULL) {
        hard_p2 = totp;   // all negatives selected
    } else {
        int ls = 63 - __builtin_clzll(bal);
        float run  = __shfl(sufc, ls, 64);
        float runp = __shfl(sufp, ls, 64);
        float bc = 0.f, bp = 0.f;
        if (lane < SEG) {
            int idx = b * NBINS + ls * SEG + lane;
            bc = hist_cnt[idx];
            bp = hist_p2[idx];
        }
        float pc2 = bc, pp2 = bp;
        #pragma unroll
        for (int o = 1; o < 64; o <<= 1) {
            float tc = __shfl_up(pc2, o, 64);
            float tp = __shfl_up(pp2, o, 64);
            if (lane >= o) { pc2 += tc; pp2 += tp; }
        }
        float tot2c = __shfl(pc2, SEG - 1, 64);
        float tot2p = __shfl(pp2, SEG - 1, 64);
        float suf2c = tot2c - pc2;
        float suf2p = tot2p - pp2;
        bool cross2 = (lane < SEG) && (run + suf2c < n_sel) && (run + suf2c + bc >= n_sel);
        unsigned long long bal2 = __ballot(cross2);
        if (bal2 == 0ULL) {
            hard_p2 = runp + tot2p;
        } else {
            int ks = 63 - __builtin_clzll(bal2);
            float rs  = __shfl(suf2c, ks, 64);
            float rsp = __shfl(suf2p, ks, 64);
            float cc  = __shfl(bc, ks, 64);
            float cp  = __shfl(bp, ks, 64);
            float need = n_sel - (run + rs);
            hard_p2 = runp + rsp + (cc > 0.f ? cp * (need / cc) : 0.f);
        }
    }

    if (lane == 0) {
        float uni = sp2 + n_pos + hard_p2 + EPSF;
        btext[b] = 1.0f - 2.0f * sp / uni;
    }
    if (lane < NKER) {
        int idx = b * NKER + lane;
        float a = kstats[idx * 3 + 0];
        float u = kstats[idx * 3 + 1];
        float t = kstats[idx * 3 + 2];
        bkterm[idx] = 1.0f - 2.0f * a / (u + t + EPSF);
    }
}

__global__ __launch_bounds__(64) void combine_kernel(
    const float* __restrict__ btext, const float* __restrict__ bkterm,
    float* __restrict__ out)
{
    const int lane = threadIdx.x;
    float t = (lane < BB) ? btext[lane] : 0.f;
    float k = bkterm[lane];                 // 80 entries: 64 + 16
    if (lane < BB * NKER - 64) k += bkterm[64 + lane];
    #define WRED(v) { for (int o_ = 32; o_ > 0; o_ >>= 1) v += __shfl_down(v, o_, 64); }
    WRED(t) WRED(k)
    #undef WRED
    if (lane == 0) {
        float lt = t / (float)BB;
        float lk = k / (float)(BB * NKER);
        out[0] = lk + 0.5f * lt;
        out[1] = lt;
        out[2] = lk;
    }
}

extern "C" void kernel_launch(void* const* d_in, const int* in_sizes, int n_in,
                              void* d_out, int out_size, void* d_ws, size_t ws_size,
                              hipStream_t stream)
{
    const float* pred    = (const float*)d_in[0];
    const float* gt_text = (const float*)d_in[1];
    const float* gt_k    = (const float*)d_in[2];
    const float* tmask   = (const float*)d_in[3];

    float* ws = (float*)d_ws;
    float* hist_cnt = ws;
    float* hist_p2  = ws + (size_t)BB * NBINS;
    float* bstats   = ws + (size_t)2 * BB * NBINS;          // BB*4
    float* kstats   = bstats + BB * 4;                      // BB*NKER*3
    float* btext    = kstats + BB * NKER * 3;               // BB
    float* bkterm   = btext + BB;                           // BB*NKER

    size_t zero_bytes = ((size_t)2 * BB * NBINS + BB * 4 + BB * NKER * 3) * sizeof(float);
    hipMemsetAsync(d_ws, 0, zero_bytes, stream);

    dim3 grid(CHUNKS, BB), block(256);
    hipLaunchKernelGGL(pass1_kernel, grid, block, 0, stream,
                       pred, gt_text, gt_k, tmask, hist_cnt, hist_p2, bstats, kstats);
    hipLaunchKernelGGL(finalize_batch_kernel, dim3(BB), dim3(64), 0, stream,
                       hist_cnt, hist_p2, bstats, kstats, btext, bkterm);
    hipLaunchKernelGGL(combine_kernel, dim3(1), dim3(64), 0, stream,
                       btext, bkterm, (float*)d_out);
}